// Round 1
// baseline (552.123 us; speedup 1.0000x reference)
//
#include <hip/hip_runtime.h>
#include <hip/hip_bf16.h>

// Self-attention: B=4, S=4096, D=512, f32 in/out, bf16 MFMA internally.
// Pipeline: cvt(q,k,v)->bf16; Wt transpose->bf16; 3 proj GEMMs (NT);
// transpose v_proj; per batch: E=qp@kp^T (f32), softmax rows -> P bf16,
// out = P@vpT^T; final: out@Wo^T + bo -> d_out (f32).
// Workspace layout (226 MB total; guarded against small ws_size).

typedef __attribute__((ext_vector_type(8))) short bf16x8;
typedef __attribute__((ext_vector_type(4))) float f32x4;
typedef __attribute__((ext_vector_type(8))) unsigned short u16x8;

#define DEVI static __device__ __forceinline__

DEVI unsigned short f2b(float x) {
  __hip_bfloat16 h = __float2bfloat16(x);
  return __builtin_bit_cast(unsigned short, h);
}

typedef const void __attribute__((address_space(1)))* gptr_t;
typedef void __attribute__((address_space(3)))* lptr_t;

DEVI void gload_lds16(const void* g, void* l) {
  __builtin_amdgcn_global_load_lds((gptr_t)g, (lptr_t)l, 16, 0, 0);
}

// ---------------- f32 -> bf16 convert (8 elems/thread, 16B stores) --------
__global__ void cvt_f32_to_bf16(const float* __restrict__ src,
                                u16x8* __restrict__ dst, int n8) {
  int i = blockIdx.x * 256 + threadIdx.x;
  if (i >= n8) return;
  const float4* s4 = (const float4*)src;
  float4 a = s4[2 * i], b = s4[2 * i + 1];
  u16x8 o;
  o[0] = f2b(a.x); o[1] = f2b(a.y); o[2] = f2b(a.z); o[3] = f2b(a.w);
  o[4] = f2b(b.x); o[5] = f2b(b.y); o[6] = f2b(b.z); o[7] = f2b(b.w);
  dst[i] = o;
}

// ------------- W [512,512] f32 -> WT [512,512] bf16 (transpose) -----------
__global__ void wtrans_f32(const float* __restrict__ W,
                           unsigned short* __restrict__ WT) {
  __shared__ unsigned short s[32][33];
  int tx = threadIdx.x, ty = threadIdx.y;   // (32,8)
  int bx = blockIdx.x, by = blockIdx.y;
#pragma unroll
  for (int i = 0; i < 32; i += 8)
    s[ty + i][tx] = f2b(W[(by * 32 + ty + i) * 512 + bx * 32 + tx]);
  __syncthreads();
#pragma unroll
  for (int i = 0; i < 32; i += 8)
    WT[(bx * 32 + ty + i) * 512 + by * 32 + tx] = s[tx][ty + i];
}

// -------- bf16 transpose: X [rows,cols] -> XT [cols,rows], per batch ------
__global__ void btrans_bf16(const unsigned short* __restrict__ X,
                            unsigned short* __restrict__ XT, int rows, int cols) {
  __shared__ unsigned short s[32][33];
  long b = blockIdx.z;
  const unsigned short* Xb = X + b * (long)rows * cols;
  unsigned short* XTb = XT + b * (long)rows * cols;
  int tx = threadIdx.x, ty = threadIdx.y;   // (32,8)
  int c0 = blockIdx.x * 32, r0 = blockIdx.y * 32;
#pragma unroll
  for (int i = 0; i < 32; i += 8)
    s[ty + i][tx] = Xb[(long)(r0 + ty + i) * cols + c0 + tx];
  __syncthreads();
#pragma unroll
  for (int i = 0; i < 32; i += 8)
    XTb[(long)(c0 + ty + i) * rows + r0 + tx] = s[tx][ty + i];
}

// ---------------- NT GEMM: C[M,N] = A[M,K] * B[N,K]^T (+bias) -------------
// 128x128 tile, BK=64, 4 waves (2x2 of 64x64), mfma 16x16x32 bf16,
// global_load_lds width 16 with XOR-swizzled source (swizzle on read side).
template <bool OUT_BF16, bool HAS_BIAS>
__global__ void gemm_nt(const unsigned short* __restrict__ A,
                        const unsigned short* __restrict__ B,
                        void* __restrict__ Cv,
                        const float* __restrict__ bias,
                        int M, int N, int K) {
  __shared__ unsigned short As[128 * 64];
  __shared__ unsigned short Bs[128 * 64];
  const int t = threadIdx.x;
  const int lane = t & 63;
  const int wid = t >> 6;
  const int wr = wid >> 1, wc = wid & 1;
  const int lr = lane & 15, lk = lane >> 4;
  const long row0 = (long)blockIdx.y * 128;
  const long col0 = (long)blockIdx.x * 128;

  f32x4 acc[4][4] = {};

  for (int k0 = 0; k0 < K; k0 += 64) {
#pragma unroll
    for (int p = 0; p < 4; ++p) {
      int gg = p * 256 + t;
      int r = gg >> 3, c = gg & 7;
      int cs = c ^ (r & 7);
      gload_lds16(A + (row0 + r) * (long)K + k0 + cs * 8, (char*)As + gg * 16);
    }
#pragma unroll
    for (int p = 0; p < 4; ++p) {
      int gg = p * 256 + t;
      int r = gg >> 3, c = gg & 7;
      int cs = c ^ (r & 7);
      gload_lds16(B + (col0 + r) * (long)K + k0 + cs * 8, (char*)Bs + gg * 16);
    }
    __syncthreads();
#pragma unroll
    for (int ks = 0; ks < 2; ++ks) {
      bf16x8 af[4], bfr[4];
#pragma unroll
      for (int mi = 0; mi < 4; ++mi) {
        int row = wr * 64 + mi * 16 + lr;
        int cc = (ks * 4 + lk) ^ (row & 7);
        af[mi] = *(const bf16x8*)((const char*)As + row * 128 + cc * 16);
      }
#pragma unroll
      for (int ni = 0; ni < 4; ++ni) {
        int row = wc * 64 + ni * 16 + lr;
        int cc = (ks * 4 + lk) ^ (row & 7);
        bfr[ni] = *(const bf16x8*)((const char*)Bs + row * 128 + cc * 16);
      }
#pragma unroll
      for (int mi = 0; mi < 4; ++mi)
#pragma unroll
        for (int ni = 0; ni < 4; ++ni)
          acc[mi][ni] = __builtin_amdgcn_mfma_f32_16x16x32_bf16(
              af[mi], bfr[ni], acc[mi][ni], 0, 0, 0);
    }
    __syncthreads();
  }

#pragma unroll
  for (int mi = 0; mi < 4; ++mi) {
#pragma unroll
    for (int ni = 0; ni < 4; ++ni) {
#pragma unroll
      for (int r = 0; r < 4; ++r) {
        long row = row0 + wr * 64 + mi * 16 + lk * 4 + r;
        long col = col0 + wc * 64 + ni * 16 + lr;
        float v = acc[mi][ni][r];
        if (HAS_BIAS) v += bias[col];
        if (OUT_BF16)
          ((unsigned short*)Cv)[row * N + col] = f2b(v);
        else
          ((float*)Cv)[row * N + col] = v;
      }
    }
  }
}

// -------- row softmax: E [4096,4096] f32 -> P bf16, scale 1/sqrt(512) -----
__global__ __launch_bounds__(256) void softmax_rows(
    const float* __restrict__ E, unsigned short* __restrict__ P) {
  const int S = 4096;
  long row = blockIdx.x;
  const float4* e4 = (const float4*)(E + row * S);
  int t = threadIdx.x;
  float v[16];
  float m = -3.0e38f;
#pragma unroll
  for (int p = 0; p < 4; ++p) {
    float4 x = e4[t + p * 256];
    v[4 * p + 0] = x.x; v[4 * p + 1] = x.y;
    v[4 * p + 2] = x.z; v[4 * p + 3] = x.w;
    m = fmaxf(m, fmaxf(fmaxf(x.x, x.y), fmaxf(x.z, x.w)));
  }
#pragma unroll
  for (int off = 32; off; off >>= 1) m = fmaxf(m, __shfl_xor(m, off));
  __shared__ float redm[4], reds[4];
  if ((t & 63) == 0) redm[t >> 6] = m;
  __syncthreads();
  m = fmaxf(fmaxf(redm[0], redm[1]), fmaxf(redm[2], redm[3]));
  const float scale = 0.04419417382415922f;  // 1/sqrt(512)
  float s = 0.f;
#pragma unroll
  for (int i = 0; i < 16; ++i) {
    v[i] = __expf((v[i] - m) * scale);
    s += v[i];
  }
#pragma unroll
  for (int off = 32; off; off >>= 1) s += __shfl_xor(s, off);
  if ((t & 63) == 0) reds[t >> 6] = s;
  __syncthreads();
  float inv = 1.0f / (reds[0] + reds[1] + reds[2] + reds[3]);
  ushort4* p4 = (ushort4*)(P + row * S);
#pragma unroll
  for (int p = 0; p < 4; ++p) {
    ushort4 o;
    o.x = f2b(v[4 * p + 0] * inv);
    o.y = f2b(v[4 * p + 1] * inv);
    o.z = f2b(v[4 * p + 2] * inv);
    o.w = f2b(v[4 * p + 3] * inv);
    p4[t + p * 256] = o;
  }
}

extern "C" void kernel_launch(void* const* d_in, const int* in_sizes, int n_in,
                              void* d_out, int out_size, void* d_ws, size_t ws_size,
                              hipStream_t stream) {
  const float* k_in = (const float*)d_in[0];
  const float* v_in = (const float*)d_in[1];
  const float* q_in = (const float*)d_in[2];
  const float* Wk = (const float*)d_in[3];
  const float* bk = (const float*)d_in[4];
  const float* Wv = (const float*)d_in[5];
  const float* bv = (const float*)d_in[6];
  const float* Wq = (const float*)d_in[7];
  const float* bq = (const float*)d_in[8];
  const float* Wo = (const float*)d_in[9];
  const float* bo = (const float*)d_in[10];

  const int B = 4, S = 4096, D = 512;
  const long BS = (long)B * S;  // 16384 rows total
  const size_t MB = 1024 * 1024;
  if (ws_size < 226 * MB) return;  // leaves d_out poisoned -> visible failure

  char* ws = (char*)d_ws;
  unsigned short* XK  = (unsigned short*)(ws + 0);
  unsigned short* XV  = (unsigned short*)(ws + 16 * MB);
  unsigned short* XQ  = (unsigned short*)(ws + 32 * MB);
  unsigned short* WTK = (unsigned short*)(ws + 48 * MB);
  unsigned short* WTV = WTK + 512 * 512;
  unsigned short* WTQ = WTV + 512 * 512;
  unsigned short* WTO = WTQ + 512 * 512;
  unsigned short* KP  = (unsigned short*)(ws + 50 * MB);
  unsigned short* VP  = (unsigned short*)(ws + 66 * MB);
  unsigned short* QP  = (unsigned short*)(ws + 82 * MB);
  unsigned short* VPT = (unsigned short*)(ws + 98 * MB);
  unsigned short* AO  = (unsigned short*)(ws + 114 * MB);
  float* EBUF         = (float*)(ws + 130 * MB);          // 64 MB, reused per batch
  unsigned short* PBUF = (unsigned short*)(ws + 194 * MB); // 32 MB, reused per batch

  int n8 = (int)(BS * D / 8);
  int cvb = (n8 + 255) / 256;
  cvt_f32_to_bf16<<<cvb, 256, 0, stream>>>(k_in, (u16x8*)XK, n8);
  cvt_f32_to_bf16<<<cvb, 256, 0, stream>>>(v_in, (u16x8*)XV, n8);
  cvt_f32_to_bf16<<<cvb, 256, 0, stream>>>(q_in, (u16x8*)XQ, n8);

  dim3 wb(32, 8), wg(16, 16);
  wtrans_f32<<<wg, wb, 0, stream>>>(Wk, WTK);
  wtrans_f32<<<wg, wb, 0, stream>>>(Wv, WTV);
  wtrans_f32<<<wg, wb, 0, stream>>>(Wq, WTQ);
  wtrans_f32<<<wg, wb, 0, stream>>>(Wo, WTO);

  dim3 gproj(D / 128, BS / 128);  // (4, 128)
  gemm_nt<true, true><<<gproj, 256, 0, stream>>>(XK, WTK, KP, bk, (int)BS, D, D);
  gemm_nt<true, true><<<gproj, 256, 0, stream>>>(XV, WTV, VP, bv, (int)BS, D, D);
  gemm_nt<true, true><<<gproj, 256, 0, stream>>>(XQ, WTQ, QP, bq, (int)BS, D, D);

  dim3 tb(32, 8), tg(D / 32, S / 32, B);  // (16,128,4)
  btrans_bf16<<<tg, tb, 0, stream>>>(VP, VPT, S, D);

  for (int b = 0; b < B; ++b) {
    const unsigned short* qpb = QP + (long)b * S * D;
    const unsigned short* kpb = KP + (long)b * S * D;
    const unsigned short* vptb = VPT + (long)b * S * D;
    unsigned short* aob = AO + (long)b * S * D;
    dim3 ge(S / 128, S / 128);  // 32x32
    gemm_nt<false, false><<<ge, 256, 0, stream>>>(qpb, kpb, EBUF, nullptr, S, S, D);
    softmax_rows<<<S, 256, 0, stream>>>(EBUF, PBUF);
    dim3 gpv(D / 128, S / 128);  // 4x32
    gemm_nt<true, false><<<gpv, 256, 0, stream>>>(PBUF, vptb, aob, nullptr, S, D, S);
  }

  dim3 gfin(D / 128, BS / 128);
  gemm_nt<false, true><<<gfin, 256, 0, stream>>>(AO, WTO, d_out, bo, (int)BS, D, D);
}

// Round 2
// 421.881 us; speedup vs baseline: 1.3087x; 1.3087x over previous
//
#include <hip/hip_runtime.h>
#include <hip/hip_bf16.h>

// Self-attention: B=4, S=4096, D=512, f32 in/out, bf16 MFMA internally.
// Pipeline: cvt(q,k,v)->bf16; W transpose->bf16; batched proj GEMM (NT, z=3);
// transpose v_proj; per batch: E=qp@kp^T (f32), softmax rows -> P bf16,
// pairwise-batched PV (z=2); final: out@Wo^T + bo -> d_out (f32).
// GEMM: 128x128 tile, BK=64, 4 waves, 2-phase double-buffered prefetch,
// XCD-bijective block swizzle, global_load_lds w=16, XOR-swizzled LDS.

typedef __attribute__((ext_vector_type(8))) short bf16x8;
typedef __attribute__((ext_vector_type(4))) float f32x4;
typedef __attribute__((ext_vector_type(8))) unsigned short u16x8;

#define DEVI static __device__ __forceinline__

DEVI unsigned short f2b(float x) {
  __hip_bfloat16 h = __float2bfloat16(x);
  return __builtin_bit_cast(unsigned short, h);
}

typedef const void __attribute__((address_space(1)))* gptr_t;
typedef void __attribute__((address_space(3)))* lptr_t;

DEVI void gload_lds16(const void* g, void* l) {
  __builtin_amdgcn_global_load_lds((gptr_t)g, (lptr_t)l, 16, 0, 0);
}

// ---------------- f32 -> bf16 convert (8 elems/thread, 16B stores) --------
__global__ void cvt_f32_to_bf16(const float* __restrict__ src,
                                u16x8* __restrict__ dst, int n8) {
  int i = blockIdx.x * 256 + threadIdx.x;
  if (i >= n8) return;
  const float4* s4 = (const float4*)src;
  float4 a = s4[2 * i], b = s4[2 * i + 1];
  u16x8 o;
  o[0] = f2b(a.x); o[1] = f2b(a.y); o[2] = f2b(a.z); o[3] = f2b(a.w);
  o[4] = f2b(b.x); o[5] = f2b(b.y); o[6] = f2b(b.z); o[7] = f2b(b.w);
  dst[i] = o;
}

// ------------- W [512,512] f32 -> WT [512,512] bf16 (transpose) -----------
__global__ void wtrans_f32(const float* __restrict__ W,
                           unsigned short* __restrict__ WT) {
  __shared__ unsigned short s[32][33];
  int tx = threadIdx.x, ty = threadIdx.y;   // (32,8)
  int bx = blockIdx.x, by = blockIdx.y;
#pragma unroll
  for (int i = 0; i < 32; i += 8)
    s[ty + i][tx] = f2b(W[(by * 32 + ty + i) * 512 + bx * 32 + tx]);
  __syncthreads();
#pragma unroll
  for (int i = 0; i < 32; i += 8)
    WT[(bx * 32 + ty + i) * 512 + by * 32 + tx] = s[tx][ty + i];
}

// -------- bf16 transpose: X [rows,cols] -> XT [cols,rows], per batch ------
__global__ void btrans_bf16(const unsigned short* __restrict__ X,
                            unsigned short* __restrict__ XT, int rows, int cols) {
  __shared__ unsigned short s[32][33];
  long b = blockIdx.z;
  const unsigned short* Xb = X + b * (long)rows * cols;
  unsigned short* XTb = XT + b * (long)rows * cols;
  int tx = threadIdx.x, ty = threadIdx.y;   // (32,8)
  int c0 = blockIdx.x * 32, r0 = blockIdx.y * 32;
#pragma unroll
  for (int i = 0; i < 32; i += 8)
    s[ty + i][tx] = Xb[(long)(r0 + ty + i) * cols + c0 + tx];
  __syncthreads();
#pragma unroll
  for (int i = 0; i < 32; i += 8)
    XTb[(long)(c0 + ty + i) * rows + r0 + tx] = s[tx][ty + i];
}

// ---------------- NT GEMM: C[M,N] = A[M,K] * B[N,K]^T (+bias) -------------
// z-batched via element strides sA/sB/sC; bias selected per z.
template <bool OUT_BF16, bool HAS_BIAS>
__global__ __launch_bounds__(256) void gemm_nt(
    const unsigned short* __restrict__ A,
    const unsigned short* __restrict__ B,
    void* __restrict__ Cv,
    const float* __restrict__ bias0,
    const float* __restrict__ bias1,
    const float* __restrict__ bias2,
    int M, int N, int K, long sA, long sB, long sC) {
  __shared__ unsigned short As[2][128 * 64];
  __shared__ unsigned short Bs[2][128 * 64];

  // XCD-bijective swizzle: chunk the row-major block order per XCD.
  const int gx = gridDim.x, gy = gridDim.y;
  const int nwg = gx * gy * gridDim.z;     // all launches have nwg % 8 == 0
  const int orig = (blockIdx.z * gy + blockIdx.y) * gx + blockIdx.x;
  const int qch = nwg >> 3;
  const int wg = (orig & 7) * qch + (orig >> 3);
  const int bx = wg % gx;
  const int tmp = wg / gx;
  const int by = tmp % gy;
  const int bz = tmp / gy;

  const unsigned short* Ab = A + (long)bz * sA;
  const unsigned short* Bb = B + (long)bz * sB;
  const float* bias = bz == 0 ? bias0 : (bz == 1 ? bias1 : bias2);

  const int t = threadIdx.x;
  const int lane = t & 63;
  const int wid = t >> 6;
  const int wr = wid >> 1, wc = wid & 1;
  const int lr = lane & 15, lk = lane >> 4;
  const long row0 = (long)by * 128;
  const long col0 = (long)bx * 128;
  const int r_ = t >> 3, c_ = t & 7;

  f32x4 acc[4][4] = {};

  auto stage = [&](int buf, int k0) {
#pragma unroll
    for (int p = 0; p < 4; ++p) {
      int r = p * 32 + r_;
      int cs = c_ ^ (r & 7);
      gload_lds16(Ab + (row0 + r) * (long)K + k0 + cs * 8,
                  (char*)As[buf] + (p * 256 + t) * 16);
    }
#pragma unroll
    for (int p = 0; p < 4; ++p) {
      int r = p * 32 + r_;
      int cs = c_ ^ (r & 7);
      gload_lds16(Bb + (col0 + r) * (long)K + k0 + cs * 8,
                  (char*)Bs[buf] + (p * 256 + t) * 16);
    }
  };

  const int nt = K >> 6;
  stage(0, 0);
  __syncthreads();             // buf0 ready
  int cur = 0;
  for (int tt = 0; tt < nt; ++tt) {
    if (tt + 1 < nt) stage(cur ^ 1, (tt + 1) << 6);   // prefetch in flight
#pragma unroll
    for (int ks = 0; ks < 2; ++ks) {
      bf16x8 af[4], bfr[4];
#pragma unroll
      for (int mi = 0; mi < 4; ++mi) {
        int row = wr * 64 + mi * 16 + lr;
        int cc = (ks * 4 + lk) ^ (row & 7);
        af[mi] = *(const bf16x8*)((const char*)As[cur] + row * 128 + cc * 16);
      }
#pragma unroll
      for (int ni = 0; ni < 4; ++ni) {
        int row = wc * 64 + ni * 16 + lr;
        int cc = (ks * 4 + lk) ^ (row & 7);
        bfr[ni] = *(const bf16x8*)((const char*)Bs[cur] + row * 128 + cc * 16);
      }
#pragma unroll
      for (int mi = 0; mi < 4; ++mi)
#pragma unroll
        for (int ni = 0; ni < 4; ++ni)
          acc[mi][ni] = __builtin_amdgcn_mfma_f32_16x16x32_bf16(
              af[mi], bfr[ni], acc[mi][ni], 0, 0, 0);
    }
    __syncthreads();           // drains prefetch (vmcnt 0) + LDS reads
    cur ^= 1;
  }

#pragma unroll
  for (int mi = 0; mi < 4; ++mi) {
#pragma unroll
    for (int ni = 0; ni < 4; ++ni) {
#pragma unroll
      for (int r = 0; r < 4; ++r) {
        long row = row0 + wr * 64 + mi * 16 + lk * 4 + r;
        long col = col0 + wc * 64 + ni * 16 + lr;
        float v = acc[mi][ni][r];
        if (HAS_BIAS) v += bias[col];
        if (OUT_BF16)
          ((unsigned short*)Cv + bz * sC)[row * N + col] = f2b(v);
        else
          ((float*)Cv + bz * sC)[row * N + col] = v;
      }
    }
  }
}

// -------- row softmax: E [4096,4096] f32 -> P bf16, scale 1/sqrt(512) -----
__global__ __launch_bounds__(256) void softmax_rows(
    const float* __restrict__ E, unsigned short* __restrict__ P) {
  const int S = 4096;
  long row = blockIdx.x;
  const float4* e4 = (const float4*)(E + row * S);
  int t = threadIdx.x;
  float v[16];
  float m = -3.0e38f;
#pragma unroll
  for (int p = 0; p < 4; ++p) {
    float4 x = e4[t + p * 256];
    v[4 * p + 0] = x.x; v[4 * p + 1] = x.y;
    v[4 * p + 2] = x.z; v[4 * p + 3] = x.w;
    m = fmaxf(m, fmaxf(fmaxf(x.x, x.y), fmaxf(x.z, x.w)));
  }
#pragma unroll
  for (int off = 32; off; off >>= 1) m = fmaxf(m, __shfl_xor(m, off));
  __shared__ float redm[4], reds[4];
  if ((t & 63) == 0) redm[t >> 6] = m;
  __syncthreads();
  m = fmaxf(fmaxf(redm[0], redm[1]), fmaxf(redm[2], redm[3]));
  const float scale = 0.04419417382415922f;  // 1/sqrt(512)
  float s = 0.f;
#pragma unroll
  for (int i = 0; i < 16; ++i) {
    v[i] = __expf((v[i] - m) * scale);
    s += v[i];
  }
#pragma unroll
  for (int off = 32; off; off >>= 1) s += __shfl_xor(s, off);
  if ((t & 63) == 0) reds[t >> 6] = s;
  __syncthreads();             // race fix: all partial sums visible
  float inv = 1.0f / (reds[0] + reds[1] + reds[2] + reds[3]);
  ushort4* p4 = (ushort4*)(P + row * S);
#pragma unroll
  for (int p = 0; p < 4; ++p) {
    ushort4 o;
    o.x = f2b(v[4 * p + 0] * inv);
    o.y = f2b(v[4 * p + 1] * inv);
    o.z = f2b(v[4 * p + 2] * inv);
    o.w = f2b(v[4 * p + 3] * inv);
    p4[t + p * 256] = o;
  }
}

extern "C" void kernel_launch(void* const* d_in, const int* in_sizes, int n_in,
                              void* d_out, int out_size, void* d_ws, size_t ws_size,
                              hipStream_t stream) {
  const float* k_in = (const float*)d_in[0];
  const float* v_in = (const float*)d_in[1];
  const float* q_in = (const float*)d_in[2];
  const float* Wk = (const float*)d_in[3];
  const float* bk = (const float*)d_in[4];
  const float* Wv = (const float*)d_in[5];
  const float* bv = (const float*)d_in[6];
  const float* Wq = (const float*)d_in[7];
  const float* bq = (const float*)d_in[8];
  const float* Wo = (const float*)d_in[9];
  const float* bo = (const float*)d_in[10];

  const int B = 4, S = 4096, D = 512;
  const long BS = (long)B * S;  // 16384
  const size_t MB = 1024 * 1024;
  if (ws_size < 226 * MB) return;  // leaves d_out poisoned -> visible failure

  char* ws = (char*)d_ws;
  unsigned short* XK  = (unsigned short*)(ws + 0);          // dead after proj
  unsigned short* XV  = (unsigned short*)(ws + 16 * MB);    // dead after proj
  unsigned short* XQ  = (unsigned short*)(ws + 32 * MB);    // dead after proj
  unsigned short* KP  = (unsigned short*)(ws + 48 * MB);
  unsigned short* VP  = (unsigned short*)(ws + 64 * MB);    // dead after btrans
  unsigned short* QP  = (unsigned short*)(ws + 80 * MB);
  unsigned short* VPT = (unsigned short*)(ws + 96 * MB);
  unsigned short* AO  = (unsigned short*)(ws + 112 * MB);
  unsigned short* WTK = (unsigned short*)(ws + 128 * MB);
  unsigned short* WTV = WTK + 512 * 512;
  unsigned short* WTQ = WTV + 512 * 512;
  unsigned short* WTO = WTQ + 512 * 512;
  float* EBUF          = (float*)(ws + 130 * MB);           // 64 MB, reused
  unsigned short* P0   = (unsigned short*)(ws + 194 * MB);  // 32 MB
  unsigned short* P1   = (unsigned short*)(ws + 0);         // 32 MB (reuse XK/XV)

  int n8 = (int)(BS * D / 8);
  int cvb = (n8 + 255) / 256;
  cvt_f32_to_bf16<<<cvb, 256, 0, stream>>>(k_in, (u16x8*)XK, n8);
  cvt_f32_to_bf16<<<cvb, 256, 0, stream>>>(v_in, (u16x8*)XV, n8);
  cvt_f32_to_bf16<<<cvb, 256, 0, stream>>>(q_in, (u16x8*)XQ, n8);

  dim3 wb(32, 8), wg(16, 16);
  wtrans_f32<<<wg, wb, 0, stream>>>(Wk, WTK);
  wtrans_f32<<<wg, wb, 0, stream>>>(Wv, WTV);
  wtrans_f32<<<wg, wb, 0, stream>>>(Wq, WTQ);
  wtrans_f32<<<wg, wb, 0, stream>>>(Wo, WTO);

  // Batched K/V/Q projections: z selects (XK,WTK,KP,bk) / (XV,..) / (XQ,..).
  gemm_nt<true, true><<<dim3(D / 128, BS / 128, 3), 256, 0, stream>>>(
      XK, WTK, KP, bk, bv, bq, (int)BS, D, D,
      BS * D, (long)D * D, BS * D);

  dim3 tb(32, 8), tg(D / 32, S / 32, B);
  btrans_bf16<<<tg, tb, 0, stream>>>(VP, VPT, S, D);

  const long sP = (long)(P1 - P0);  // negative stride between P buffers
  for (int pair = 0; pair < 4; pair += 2) {
    for (int j = 0; j < 2; ++j) {
      int b = pair + j;
      const unsigned short* qpb = QP + (long)b * S * D;
      const unsigned short* kpb = KP + (long)b * S * D;
      gemm_nt<false, false><<<dim3(S / 128, S / 128, 1), 256, 0, stream>>>(
          qpb, kpb, EBUF, nullptr, nullptr, nullptr, S, S, D, 0, 0, 0);
      softmax_rows<<<S, 256, 0, stream>>>(EBUF, j == 0 ? P0 : P1);
    }
    // PV for the pair, z-batched: A = P0 / P1, B = VPT[b], C = AO[b].
    gemm_nt<true, false><<<dim3(D / 128, S / 128, 2), 256, 0, stream>>>(
        P0, VPT + (long)pair * S * D, AO + (long)pair * S * D,
        nullptr, nullptr, nullptr, S, D, S,
        sP, (long)S * D, (long)S * D);
  }

  gemm_nt<false, true><<<dim3(D / 128, BS / 128, 1), 256, 0, stream>>>(
      AO, WTO, d_out, bo, nullptr, nullptr, (int)BS, D, D, 0, 0, 0);
}

// Round 3
// 321.446 us; speedup vs baseline: 1.7176x; 1.3124x over previous
//
#include <hip/hip_runtime.h>
#include <hip/hip_bf16.h>

// Self-attention: B=4, S=4096, D=512, f32 in/out, bf16 MFMA internally.
// cvt(q,k,v)->bf16 (z=3); W transpose->bf16 (z=4); proj GEMM (NT, z=3);
// btrans v_proj; per batch: E=qp@kp^T (bf16), softmax -> P[b] bf16;
// one PV GEMM (z=4); final out@Wo^T + bo -> d_out (f32).
// GEMM: 128x128 tile, BK=64, 4 waves, double-buffered LDS with COUNTED
// vmcnt(8) prefetch (never drains to 0 in the loop), raw s_barrier,
// XCD-bijective block swizzle, global_load_lds w=16, XOR-swizzled LDS.

typedef __attribute__((ext_vector_type(8))) short bf16x8;
typedef __attribute__((ext_vector_type(4))) float f32x4;
typedef __attribute__((ext_vector_type(8))) unsigned short u16x8;

#define DEVI static __device__ __forceinline__

DEVI unsigned short f2b(float x) {
  __hip_bfloat16 h = __float2bfloat16(x);
  return __builtin_bit_cast(unsigned short, h);
}
DEVI float b2f(unsigned short x) {
  return __builtin_bit_cast(float, (unsigned)x << 16);
}

typedef const void __attribute__((address_space(1)))* gptr_t;
typedef void __attribute__((address_space(3)))* lptr_t;

DEVI void gload_lds16(const void* g, void* l) {
  __builtin_amdgcn_global_load_lds((gptr_t)g, (lptr_t)l, 16, 0, 0);
}

// ------------- f32 -> bf16 convert, z selects (k,v,q) -> contiguous dst ---
__global__ void cvt3_f32_to_bf16(const float* __restrict__ s0,
                                 const float* __restrict__ s1,
                                 const float* __restrict__ s2,
                                 u16x8* __restrict__ dst, int n8) {
  int i = blockIdx.x * 256 + threadIdx.x;
  if (i >= n8) return;
  const float* src = blockIdx.z == 0 ? s0 : (blockIdx.z == 1 ? s1 : s2);
  const float4* s4 = (const float4*)src;
  float4 a = s4[2 * i], b = s4[2 * i + 1];
  u16x8 o;
  o[0] = f2b(a.x); o[1] = f2b(a.y); o[2] = f2b(a.z); o[3] = f2b(a.w);
  o[4] = f2b(b.x); o[5] = f2b(b.y); o[6] = f2b(b.z); o[7] = f2b(b.w);
  dst[(long)blockIdx.z * n8 + i] = o;
}

// ---- W [512,512] f32 -> WT [512,512] bf16 transpose, z selects W ---------
__global__ void wtrans4_f32(const float* __restrict__ w0,
                            const float* __restrict__ w1,
                            const float* __restrict__ w2,
                            const float* __restrict__ w3,
                            unsigned short* __restrict__ WT) {
  __shared__ unsigned short s[32][33];
  const float* W = blockIdx.z == 0 ? w0 : (blockIdx.z == 1 ? w1
                   : (blockIdx.z == 2 ? w2 : w3));
  unsigned short* dst = WT + (long)blockIdx.z * 512 * 512;
  int tx = threadIdx.x, ty = threadIdx.y;   // (32,8)
  int bx = blockIdx.x, by = blockIdx.y;
#pragma unroll
  for (int i = 0; i < 32; i += 8)
    s[ty + i][tx] = f2b(W[(by * 32 + ty + i) * 512 + bx * 32 + tx]);
  __syncthreads();
#pragma unroll
  for (int i = 0; i < 32; i += 8)
    dst[(bx * 32 + ty + i) * 512 + by * 32 + tx] = s[tx][ty + i];
}

// -------- bf16 transpose: X [rows,cols] -> XT [cols,rows], per batch ------
__global__ void btrans_bf16(const unsigned short* __restrict__ X,
                            unsigned short* __restrict__ XT, int rows, int cols) {
  __shared__ unsigned short s[32][33];
  long b = blockIdx.z;
  const unsigned short* Xb = X + b * (long)rows * cols;
  unsigned short* XTb = XT + b * (long)rows * cols;
  int tx = threadIdx.x, ty = threadIdx.y;   // (32,8)
  int c0 = blockIdx.x * 32, r0 = blockIdx.y * 32;
#pragma unroll
  for (int i = 0; i < 32; i += 8)
    s[ty + i][tx] = Xb[(long)(r0 + ty + i) * cols + c0 + tx];
  __syncthreads();
#pragma unroll
  for (int i = 0; i < 32; i += 8)
    XTb[(long)(c0 + ty + i) * rows + r0 + tx] = s[tx][ty + i];
}

// ---------------- NT GEMM: C[M,N] = A[M,K] * B[N,K]^T (+bias) -------------
// z-batched via element strides sA/sB/sC; bias selected per z.
template <bool OUT_BF16, bool HAS_BIAS>
__global__ __launch_bounds__(256) void gemm_nt(
    const unsigned short* __restrict__ A,
    const unsigned short* __restrict__ B,
    void* __restrict__ Cv,
    const float* __restrict__ bias0,
    const float* __restrict__ bias1,
    const float* __restrict__ bias2,
    int M, int N, int K, long sA, long sB, long sC) {
  __shared__ unsigned short As[2][128 * 64];
  __shared__ unsigned short Bs[2][128 * 64];

  // XCD-bijective swizzle (nwg % 8 == 0 for every launch).
  const int gx = gridDim.x, gy = gridDim.y;
  const int nwg = gx * gy * gridDim.z;
  const int orig = (blockIdx.z * gy + blockIdx.y) * gx + blockIdx.x;
  const int qch = nwg >> 3;
  const int wg = (orig & 7) * qch + (orig >> 3);
  const int bx = wg % gx;
  const int tmp = wg / gx;
  const int by = tmp % gy;
  const int bz = tmp / gy;

  const unsigned short* Ab = A + (long)bz * sA;
  const unsigned short* Bb = B + (long)bz * sB;
  const float* bias = bz == 0 ? bias0 : (bz == 1 ? bias1 : bias2);

  const int t = threadIdx.x;
  const int lane = t & 63;
  const int wid = t >> 6;
  const int wr = wid >> 1, wc = wid & 1;
  const int lr = lane & 15, lk = lane >> 4;
  const long row0 = (long)by * 128;
  const long col0 = (long)bx * 128;
  const int r_ = t >> 3, c_ = t & 7;

  f32x4 acc[4][4] = {};

  auto stage = [&](int buf, int k0) {
#pragma unroll
    for (int p = 0; p < 4; ++p) {
      int r = p * 32 + r_;
      int cs = c_ ^ (r & 7);
      gload_lds16(Ab + (row0 + r) * (long)K + k0 + cs * 8,
                  (char*)As[buf] + (p * 256 + t) * 16);
    }
#pragma unroll
    for (int p = 0; p < 4; ++p) {
      int r = p * 32 + r_;
      int cs = c_ ^ (r & 7);
      gload_lds16(Bb + (col0 + r) * (long)K + k0 + cs * 8,
                  (char*)Bs[buf] + (p * 256 + t) * 16);
    }
  };

  const int nt = K >> 6;
  stage(0, 0);
  int cur = 0;
  for (int tt = 0; tt < nt; ++tt) {
    if (tt + 1 < nt) {
      stage(cur ^ 1, (tt + 1) << 6);  // 8 more loads in flight
      asm volatile("s_waitcnt vmcnt(8)" ::: "memory");  // cur's loads landed
    } else {
      asm volatile("s_waitcnt vmcnt(0)" ::: "memory");
    }
    __builtin_amdgcn_s_barrier();
#pragma unroll
    for (int ks = 0; ks < 2; ++ks) {
      bf16x8 af[4], bfr[4];
#pragma unroll
      for (int mi = 0; mi < 4; ++mi) {
        int row = wr * 64 + mi * 16 + lr;
        int cc = (ks * 4 + lk) ^ (row & 7);
        af[mi] = *(const bf16x8*)((const char*)As[cur] + row * 128 + cc * 16);
      }
#pragma unroll
      for (int ni = 0; ni < 4; ++ni) {
        int row = wc * 64 + ni * 16 + lr;
        int cc = (ks * 4 + lk) ^ (row & 7);
        bfr[ni] = *(const bf16x8*)((const char*)Bs[cur] + row * 128 + cc * 16);
      }
#pragma unroll
      for (int mi = 0; mi < 4; ++mi)
#pragma unroll
        for (int ni = 0; ni < 4; ++ni)
          acc[mi][ni] = __builtin_amdgcn_mfma_f32_16x16x32_bf16(
              af[mi], bfr[ni], acc[mi][ni], 0, 0, 0);
    }
    // ds_reads retired before other waves may overwrite this buffer:
    asm volatile("s_waitcnt lgkmcnt(0)" ::: "memory");
    __builtin_amdgcn_s_barrier();
    cur ^= 1;
  }

#pragma unroll
  for (int mi = 0; mi < 4; ++mi) {
#pragma unroll
    for (int ni = 0; ni < 4; ++ni) {
#pragma unroll
      for (int r = 0; r < 4; ++r) {
        long row = row0 + wr * 64 + mi * 16 + lk * 4 + r;
        long col = col0 + wc * 64 + ni * 16 + lr;
        float v = acc[mi][ni][r];
        if (HAS_BIAS) v += bias[col];
        if (OUT_BF16)
          ((unsigned short*)Cv + bz * sC)[row * N + col] = f2b(v);
        else
          ((float*)Cv + bz * sC)[row * N + col] = v;
      }
    }
  }
}

// ---- row softmax: E [4096,4096] bf16 -> P bf16, scale 1/sqrt(512) --------
__global__ __launch_bounds__(256) void softmax_rows_bf16(
    const unsigned short* __restrict__ E, unsigned short* __restrict__ P) {
  const int S = 4096;
  long row = blockIdx.x;
  const u16x8* e8 = (const u16x8*)(E + row * S);
  int t = threadIdx.x;
  float v[16];
  float m = -3.0e38f;
#pragma unroll
  for (int p = 0; p < 2; ++p) {
    u16x8 x = e8[t + p * 256];
#pragma unroll
    for (int j = 0; j < 8; ++j) {
      float f = b2f((unsigned short)x[j]);
      v[8 * p + j] = f;
      m = fmaxf(m, f);
    }
  }
#pragma unroll
  for (int off = 32; off; off >>= 1) m = fmaxf(m, __shfl_xor(m, off));
  __shared__ float redm[4], reds[4];
  if ((t & 63) == 0) redm[t >> 6] = m;
  __syncthreads();
  m = fmaxf(fmaxf(redm[0], redm[1]), fmaxf(redm[2], redm[3]));
  const float scale = 0.04419417382415922f;  // 1/sqrt(512)
  float s = 0.f;
#pragma unroll
  for (int i = 0; i < 16; ++i) {
    v[i] = __expf((v[i] - m) * scale);
    s += v[i];
  }
#pragma unroll
  for (int off = 32; off; off >>= 1) s += __shfl_xor(s, off);
  if ((t & 63) == 0) reds[t >> 6] = s;
  __syncthreads();
  float inv = 1.0f / (reds[0] + reds[1] + reds[2] + reds[3]);
  u16x8* p8 = (u16x8*)(P + row * S);
#pragma unroll
  for (int p = 0; p < 2; ++p) {
    u16x8 o;
#pragma unroll
    for (int j = 0; j < 8; ++j) o[j] = f2b(v[8 * p + j] * inv);
    p8[t + p * 256] = o;
  }
}

extern "C" void kernel_launch(void* const* d_in, const int* in_sizes, int n_in,
                              void* d_out, int out_size, void* d_ws, size_t ws_size,
                              hipStream_t stream) {
  const float* k_in = (const float*)d_in[0];
  const float* v_in = (const float*)d_in[1];
  const float* q_in = (const float*)d_in[2];
  const float* Wk = (const float*)d_in[3];
  const float* bk = (const float*)d_in[4];
  const float* Wv = (const float*)d_in[5];
  const float* bv = (const float*)d_in[6];
  const float* Wq = (const float*)d_in[7];
  const float* bq = (const float*)d_in[8];
  const float* Wo = (const float*)d_in[9];
  const float* bo = (const float*)d_in[10];

  const int B = 4, S = 4096, D = 512;
  const long BS = (long)B * S;      // 16384
  const size_t MB = 1024 * 1024;
  if (ws_size < 226 * MB) return;   // leaves d_out poisoned -> visible failure

  // Workspace layout (226 MiB), with liveness-based overlap:
  //   0..128   P0..P3 (32 MiB each; early: XK 0..16, XV 16..32, XQ 32..48)
  //   128..160 EBUF (bf16 S*S, reused per batch)
  //   160..176 VPT
  //   176..224 KP, VP, QP (uniform stride; VP -> AO after btrans)
  //   224..226 WTK,WTV,WTQ,WTO
  char* ws = (char*)d_ws;
  unsigned short* P    = (unsigned short*)(ws + 0);
  unsigned short* XK   = (unsigned short*)(ws + 0);
  unsigned short* EBUF = (unsigned short*)(ws + 128 * MB);
  unsigned short* VPT  = (unsigned short*)(ws + 160 * MB);
  unsigned short* KP   = (unsigned short*)(ws + 176 * MB);
  unsigned short* VP   = (unsigned short*)(ws + 192 * MB);
  unsigned short* QP   = (unsigned short*)(ws + 208 * MB);
  unsigned short* AO   = (unsigned short*)(ws + 192 * MB);  // reuses VP
  unsigned short* WTK  = (unsigned short*)(ws + 224 * MB);
  unsigned short* WTV  = WTK + 512 * 512;
  unsigned short* WTQ  = WTV + 512 * 512;
  unsigned short* WTO  = WTQ + 512 * 512;

  int n8 = (int)(BS * D / 8);
  cvt3_f32_to_bf16<<<dim3((n8 + 255) / 256, 1, 3), 256, 0, stream>>>(
      k_in, v_in, q_in, (u16x8*)XK, n8);

  wtrans4_f32<<<dim3(16, 16, 4), dim3(32, 8), 0, stream>>>(
      Wk, Wv, Wq, Wo, WTK);

  // Batched K/V/Q projections: z selects (XK,WTK,KP,bk)/(XV,..)/(XQ,..).
  gemm_nt<true, true><<<dim3(D / 128, BS / 128, 3), 256, 0, stream>>>(
      XK, WTK, KP, bk, bv, bq, (int)BS, D, D,
      BS * D, (long)D * D, (long)8 * MB /*16 MiB in elems*/);

  btrans_bf16<<<dim3(D / 32, S / 32, B), dim3(32, 8), 0, stream>>>(VP, VPT, S, D);

  for (int b = 0; b < B; ++b) {
    gemm_nt<true, false><<<dim3(S / 128, S / 128, 1), 256, 0, stream>>>(
        QP + (long)b * S * D, KP + (long)b * S * D, EBUF,
        nullptr, nullptr, nullptr, S, S, D, 0, 0, 0);
    softmax_rows_bf16<<<S, 256, 0, stream>>>(EBUF, P + (long)b * S * S);
  }

  // One PV dispatch, z=4: A=P[b], B=VPT[b], C=AO[b]. 512 blocks.
  gemm_nt<true, false><<<dim3(D / 128, S / 128, 4), 256, 0, stream>>>(
      P, VPT, AO, nullptr, nullptr, nullptr, S, D, S,
      (long)S * S, (long)S * D, (long)S * D);

  gemm_nt<false, true><<<dim3(D / 128, BS / 128, 1), 256, 0, stream>>>(
      AO, WTO, d_out, bo, nullptr, nullptr, (int)BS, D, D, 0, 0, 0);
}